// Round 4
// baseline (172.949 us; speedup 1.0000x reference)
//
#include <hip/hip_runtime.h>

// Lorenz RK4, B=16384, NT=2000, dt=0.01. out[b*6003 + d*2001 + t].
//
// Round-4: producer + TWO consumer waves, TT=64.
//  - 256 blocks x 192 threads (3 waves), 1 block/CU.
//  - Wave 0: computes 64 trajectories (1/lane, registers), writes each
//    step's state to LDS only. ~48 instr/step, no memory waits.
//  - Waves 1,2: drain the finished 64-step tile (rows 0-31 / 32-63) to HBM,
//    lane = time index -> 256B-contiguous stores, overlapped with wave 0
//    computing the next tile (double buffer).
//  - Math identical to rounds 2/3 (absmax 0.0078125, 10x under threshold).

#define NT     2000
#define TT     64
#define NFULL  31          // 31 full tiles of 64 steps
#define TAIL   16          // + 16-step tail
#define TROWS  2001
#define ROWS   64          // trajectories per block
#define LROWS  65          // pad -> <=2-way LDS banking everywhere

#define FMA(a,b,c) __builtin_fmaf((a),(b),(c))

__global__ __launch_bounds__(192) void lorenz_rk4(
    const float* __restrict__ x0,
    const float* __restrict__ p,
    float* __restrict__ out)
{
#pragma clang fp contract(off)
    __shared__ float buf[2][3][TT][LROWS];   // 99.8 KB

    const int tid  = threadIdx.x;
    const int lane = tid & 63;
    const int b0   = blockIdx.x * ROWS;

    if (tid < 64) {
        // ================= compute wave =================
        const float p0  = p[0], p1 = p[1], p2n = -p[2];
        const float h1 = 0.01f;
        const float h2 = 0.01f / 2.0f;
        const float h6 = 0.01f / 6.0f;
        const int b = b0 + lane;
        float x = x0[3*b + 0], y = x0[3*b + 1], z = x0[3*b + 2];

        {   // t = 0 column
            size_t g = (size_t)b * (3 * TROWS);
            out[g] = x; out[g + TROWS] = y; out[g + 2*TROWS] = z;
        }

#define STEP() do {                                                          \
        float k1x = p0 * (y - x);                                            \
        float k1y = FMA(x, p1 - z, -y);                                      \
        float k1z = FMA(p2n, z, x * y);                                      \
        float ax = FMA(h2,k1x,x), ay = FMA(h2,k1y,y), az = FMA(h2,k1z,z);    \
        float k2x = p0 * (ay - ax);                                          \
        float k2y = FMA(ax, p1 - az, -ay);                                   \
        float k2z = FMA(p2n, az, ax * ay);                                   \
        float bx = FMA(h2,k2x,x), by = FMA(h2,k2y,y), bz = FMA(h2,k2z,z);    \
        float k3x = p0 * (by - bx);                                          \
        float k3y = FMA(bx, p1 - bz, -by);                                   \
        float k3z = FMA(p2n, bz, bx * by);                                   \
        float cx = FMA(h1,k3x,x), cy = FMA(h1,k3y,y), cz = FMA(h1,k3z,z);    \
        float k4x = p0 * (cy - cx);                                          \
        float k4y = FMA(cx, p1 - cz, -cy);                                   \
        float k4z = FMA(p2n, cz, cx * cy);                                   \
        float sx = FMA(2.0f,k2x,k1x); sx = FMA(2.0f,k3x,sx); sx += k4x;      \
        float sy = FMA(2.0f,k2y,k1y); sy = FMA(2.0f,k3y,sy); sy += k4y;      \
        float sz = FMA(2.0f,k2z,k1z); sz = FMA(2.0f,k3z,sz); sz += k4z;      \
        x = FMA(h6,sx,x); y = FMA(h6,sy,y); z = FMA(h6,sz,z);                \
    } while (0)

        for (int k = 0; k < NFULL; ++k) {
            float* bb = &buf[k & 1][0][0][0];
#pragma unroll 16
            for (int tl = 0; tl < TT; ++tl) {
                STEP();
                bb[              tl*LROWS + lane] = x;
                bb[  TT*LROWS  + tl*LROWS + lane] = y;
                bb[2*TT*LROWS  + tl*LROWS + lane] = z;
            }
            __syncthreads();                  // tile k ready
        }
#pragma unroll 16
        for (int tl = 0; tl < TAIL; ++tl) {   // tail tile -> buf 1
            STEP();
            buf[1][0][tl][lane] = x;
            buf[1][1][tl][lane] = y;
            buf[1][2][tl][lane] = z;
        }
        __syncthreads();                      // tail ready
#undef STEP
    } else {
        // ================= writer waves =================
        const int w     = (tid >> 6) - 1;     // 0 or 1
        const int rbase = w * 32;             // rows [rbase, rbase+32)
        const int t     = lane;               // time within tile

        for (int k = 0; k < NFULL; ++k) {
            __syncthreads();                  // wait: tile k ready
            const float* bb = &buf[k & 1][0][0][0];
            size_t g = (size_t)(b0 + rbase) * (3 * TROWS) + 1 + (size_t)k * TT + t;
#pragma unroll 4
            for (int r = rbase; r < rbase + 32; ++r) {
                out[g]             = bb[              t*LROWS + r];
                out[g +     TROWS] = bb[  TT*LROWS  + t*LROWS + r];
                out[g + 2 * TROWS] = bb[2*TT*LROWS  + t*LROWS + r];
                g += (size_t)(3 * TROWS);
            }
        }
        __syncthreads();                      // wait: tail ready
        {
            const int tloc = lane & 15;
            int rloc = rbase + (lane >> 4);   // 4 rows per instruction
            size_t g = (size_t)(b0 + rloc) * (3 * TROWS) + 1 + (size_t)NFULL * TT + tloc;
#pragma unroll 4
            for (int i = 0; i < 8; ++i) {
                out[g]             = buf[1][0][tloc][rloc];
                out[g +     TROWS] = buf[1][1][tloc][rloc];
                out[g + 2 * TROWS] = buf[1][2][tloc][rloc];
                rloc += 4;
                g    += (size_t)4 * (3 * TROWS);
            }
        }
    }
}

extern "C" void kernel_launch(void* const* d_in, const int* in_sizes, int n_in,
                              void* d_out, int out_size, void* d_ws, size_t ws_size,
                              hipStream_t stream)
{
    const float* x0  = (const float*)d_in[0];
    const float* p   = (const float*)d_in[1];
    float*       out = (float*)d_out;

    const int B = in_sizes[0] / 3;        // 16384
    const int nblocks = B / ROWS;         // 256

    lorenz_rk4<<<nblocks, 192, 0, stream>>>(x0, p, out);
}